// Round 11
// baseline (323.260 us; speedup 1.0000x reference)
//
#include <hip/hip_runtime.h>
#include <stdint.h>

// Baum-Welch forward-backward posteriors (log_gamma), MI355X gfx950.
//
// R14 -> R15: double time-parallelism; 2 blocks/CU co-resident.
//  - R14 confirmed: chunked warmup is numerically exact (absmax identical),
//    but per-step latency is still ~2740 cy and with 1 block/CU the wall =
//    single-chain latency (127 steps). ~70% of each step is stall.
//  - CL=32, CW=32: 512 blocks (2 dir x 16 chunks x 16 seq-groups) ->
//    2 blocks/CU co-resident (VGPR 180 -> 2 waves/SIMD; LDS 19KB x 2).
//    Chain halves to 64 steps AND the partner block's waves fill stalls:
//    wall ~ max(64 x 2740 cy, issue-sum) ~ 73 us.
//  - CW=32 warmup error <= 0.5^32 ~ 2e-10 even at a conservative 0.5/step
//    Birkhoff contraction (CW=64 measured bit-identical absmax to serial).
//  - Step body, staging map, deferred-by-2 scale, macros: R14-proven,
//    unchanged. Only constants + grid mapping changed.
//  - Fallback tiers (small ws): R12's full-length kernels, unchanged.

#define NB 256
#define TT 512
#define KK 256
#define VV 4096
#define SPB 16            // sequences per block
#define NBLK (NB / SPB)   // 16 seq-groups
#define CL 32             // chunk length (rows written per chunk)
#define CW 32             // warmup steps
#define NCH (TT / CL)     // 16 chunks per direction
#define LOG2E 1.44269504088896f
#define LN2 0.693147180559945f

typedef float f4 __attribute__((ext_vector_type(4)));
typedef short b8 __attribute__((ext_vector_type(8)));
typedef unsigned int u32;
typedef u32 u2v __attribute__((ext_vector_type(2)));
typedef u32 u4v __attribute__((ext_vector_type(4)));

__device__ __forceinline__ void bar_lds() {
  asm volatile("s_waitcnt lgkmcnt(0)" ::: "memory");
  __builtin_amdgcn_s_barrier();
}

__device__ __forceinline__ unsigned short f2bf_rne(float x) {
  u32 u = __float_as_uint(x);
  return (unsigned short)((u + 0x7FFFu + ((u >> 16) & 1u)) >> 16);
}
// pack two positive floats to 2xbf16 (round-half-up) in one v_perm each.
__device__ __forceinline__ u32 pkbf(float lo, float hi) {
  return __builtin_amdgcn_perm(__float_as_uint(hi) + 0x8000u,
                               __float_as_uint(lo) + 0x8000u, 0x07060302u);
}
__device__ __forceinline__ u2v mku2(u32 a, u32 b) {
  u2v v; v[0] = a; v[1] = b; return v;
}
__device__ __forceinline__ float fmax4(const f4& v) {
  return fmaxf(fmaxf(v[0], v[1]), fmaxf(v[2], v[3]));
}

// ==================== chunked 4-wave MFMA recurrence ====================
struct Sm4c {
  unsigned short obs4[SPB][72];        // 2.3 KB chunk obs window
  b8 xfrag[2][8][64];                  // 16 KB ping-pong B fragments
  __align__(16) float smax[2][16][4];  // deferred per-seq max partials
};

// MODE 0: forward chunk -> bf16 scaled-alpha rows [wlo, wlo+CL) of outh.
// MODE 2: backward chunk -> bf16 scaled-beta rows [wlo, wlo+CL) (last chunk
//         also writes row 511 = 1).
template <int MODE>
__device__ __forceinline__ void body4c(Sm4c& sm, int n0, int c,
                                       const float* __restrict__ lpi,
                                       const float* __restrict__ lA,
                                       const float* __restrict__ ebT,
                                       const int* __restrict__ obs,
                                       unsigned short* __restrict__ outh) {
  const int tid = threadIdx.x;  // 0..255
  const int w = tid >> 6;       // wave 0..3: owns states [64w, 64w+64)
  const int l = tid & 63;
  const int n = l & 15;         // sequence slot
  const int q = l >> 4;         // 0..3
  const int jo0 = 64 * w + 4 * q;

  // Chunk ranges.
  const int wlo = c * CL;
  int t0 = 0, tEnd = 0, tS = 0, whi = 0, base, tmax;
  if (MODE == 0) {
    tEnd = wlo + CL - 1;
    t0 = (c == 0) ? 0 : wlo - CW;
    base = t0;
    tmax = tEnd;
  } else {
    whi = wlo + CL;
    tS = whi + CW - 1;
    if (tS > TT - 1) tS = TT - 1;
    base = wlo;
    tmax = tS;
  }
  const int win = tmax - base + 1;  // <= 64

  for (int i = tid; i < SPB * 64; i += 256) {
    const int s = i >> 6, k = i & 63;
    if (k < win)
      sm.obs4[s][k] = (unsigned short)obs[(size_t)(n0 + s) * TT + base + k];
  }

  // A fragments: tile = 4w+mt, m = 16*tile + n, k = kc*32 + q*8 + e.
  // fwd: expA[k][m] (A^T); bwd: expA[m][k] (A).
  b8 af[4][8];
#pragma unroll
  for (int mt = 0; mt < 4; ++mt) {
    const int m = 16 * (4 * w + mt) + n;
#pragma unroll
    for (int kc = 0; kc < 8; ++kc) {
      u4v tmp;
#pragma unroll
      for (int ep = 0; ep < 4; ++ep) {
        const int k = kc * 32 + q * 8 + 2 * ep;
        float v0, v1;
        if (MODE == 0) {
          v0 = lA[(size_t)k * KK + m];
          v1 = lA[(size_t)(k + 1) * KK + m];
        } else {
          v0 = lA[(size_t)m * KK + k];
          v1 = lA[(size_t)m * KK + k + 1];
        }
        tmp[ep] = pkbf(exp2f(v0 * LOG2E), exp2f(v1 * LOG2E));
      }
      af[mt][kc] = __builtin_bit_cast(b8, tmp);
    }
  }

  // Staging map (R10-verified): plane kc = tile>>1;
  // ushort index = 8*(n + 16*(q>>1) + 32*(tile&1)) + 4*(q&1).
  int usb[4];
#pragma unroll
  for (int mt = 0; mt < 4; ++mt) {
    const int tile = 4 * w + mt;
    usb[mt] = 8 * (n + 16 * (q >> 1) + 32 * (tile & 1)) + 4 * (q & 1);
  }
  const int kcp[4] = {(4 * w) >> 1, (4 * w) >> 1, (4 * w + 2) >> 1,
                      (4 * w + 2) >> 1};

  if (tid < 128) ((float*)sm.smax)[tid] = 1.0f;  // seed both slots
  __syncthreads();

  const size_t rown = (size_t)(n0 + n) * TT * KK;
  u32 pst[8], qst[8];
  float mloc = 0.f;
  f4 eA[4], eB[4];
  int cur = 0;

  auto emis4 = [&](int o, f4 e[4]) {
    const float* er = ebT + (size_t)o * KK + jo0;
#pragma unroll
    for (int mt = 0; mt < 4; ++mt) e[mt] = *(const f4*)(er + 16 * mt);
  };

#define MFMA4(ACC)                                                          \
  {                                                                         \
    b8 bfr[8];                                                              \
    _Pragma("unroll") for (int kc = 0; kc < 8; ++kc) bfr[kc] =              \
        sm.xfrag[cur][kc][l];                                               \
    _Pragma("unroll") for (int mt = 0; mt < 4; ++mt) {                      \
      f4 ca = {0.f, 0.f, 0.f, 0.f}, cb = ca;                                \
      _Pragma("unroll") for (int kc = 0; kc < 4; ++kc) ca =                 \
          __builtin_amdgcn_mfma_f32_16x16x32_bf16(af[mt][kc], bfr[kc], ca,  \
                                                  0, 0, 0);                 \
      _Pragma("unroll") for (int kc = 4; kc < 8; ++kc) cb =                 \
          __builtin_amdgcn_mfma_f32_16x16x32_bf16(af[mt][kc], bfr[kc], cb,  \
                                                  0, 0, 0);                 \
      ACC[mt] = ca + cb;                                                    \
    }                                                                       \
  }

#define STAGE(P)                                                            \
  _Pragma("unroll") for (int mt = 0; mt < 4; ++mt)                          \
      *(u2v*)((unsigned short*)&sm.xfrag[cur ^ 1][kcp[mt]][0] + usb[mt]) =  \
          mku2(P[2 * mt], P[2 * mt + 1]);

#define SMWR()                                                              \
  {                                                                         \
    float mm_ = fmaxf(mloc, __shfl_xor(mloc, 16));                          \
    mm_ = fmaxf(mm_, __shfl_xor(mm_, 32));                                  \
    if (l < 16) sm.smax[cur][n][w] = mm_;                                   \
  }

#define RSCALE(RS)                                                          \
  const f4 sm4_ = *(const f4*)&sm.smax[cur ^ 1][n][0];                      \
  const float RS = __builtin_amdgcn_rcpf(fmaxf(fmax4(sm4_), 1e-30f));

#define STEPF(T_, EU)                                                       \
  {                                                                         \
    const int tt_ = (T_);                                                   \
    if (tt_ >= wlo) { /* deferred store of row tt_ */                       \
      unsigned short* op_ = outh + rown + (size_t)tt_ * KK + jo0;           \
      _Pragma("unroll") for (int mt = 0; mt < 4; ++mt)                      \
          *(u2v*)(op_ + 16 * mt) = mku2(pst[2 * mt], pst[2 * mt + 1]);      \
    }                                                                       \
    SMWR()                                                                  \
    RSCALE(rs_)                                                             \
    const f4 ec0 = EU[0], ec1 = EU[1], ec2 = EU[2], ec3 = EU[3];            \
    const int o3_ = sm.obs4[n][(tt_ + 3 <= tEnd ? tt_ + 3 : tEnd) - base];  \
    emis4(o3_, EU);                                                         \
    f4 acc[4];                                                              \
    MFMA4(acc)                                                              \
    const f4 ecs_[4] = {ec0, ec1, ec2, ec3};                                \
    mloc = 0.f;                                                             \
    _Pragma("unroll") for (int mt = 0; mt < 4; ++mt) {                      \
      const f4 y_ = acc[mt] * (ecs_[mt] * rs_);                             \
      pst[2 * mt] = pkbf(y_[0], y_[1]);                                     \
      pst[2 * mt + 1] = pkbf(y_[2], y_[3]);                                 \
      mloc = fmaxf(mloc, fmax4(y_));                                        \
    }                                                                       \
    STAGE(pst)                                                              \
    bar_lds();                                                              \
    cur ^= 1;                                                               \
  }

#define STEPB(T_, EU)                                                       \
  {                                                                         \
    const int tt_ = (T_);                                                   \
    if (tt_ + 1 < whi) { /* deferred store of beta row tt_+1 */             \
      unsigned short* op_ = outh + rown + (size_t)(tt_ + 1) * KK + jo0;     \
      _Pragma("unroll") for (int mt = 0; mt < 4; ++mt)                      \
          *(u2v*)(op_ + 16 * mt) = mku2(qst[2 * mt], qst[2 * mt + 1]);      \
    }                                                                       \
    SMWR()                                                                  \
    RSCALE(rs_)                                                             \
    const f4 ec0 = EU[0], ec1 = EU[1], ec2 = EU[2], ec3 = EU[3];            \
    const int o2_ = sm.obs4[n][(tt_ >= wlo + 2 ? tt_ - 2 : wlo) - base];    \
    emis4(o2_, EU);                                                         \
    f4 acc[4];                                                              \
    MFMA4(acc)                                                              \
    const f4 ecs_[4] = {ec0, ec1, ec2, ec3};                                \
    mloc = 0.f;                                                             \
    _Pragma("unroll") for (int mt = 0; mt < 4; ++mt) {                      \
      const f4 bsc_ = acc[mt] * rs_;        /* scaled beta_t */             \
      const f4 yw_ = bsc_ * ecs_[mt];       /* staged w_t */                \
      qst[2 * mt] = pkbf(bsc_[0], bsc_[1]);                                 \
      qst[2 * mt + 1] = pkbf(bsc_[2], bsc_[3]);                             \
      pst[2 * mt] = pkbf(yw_[0], yw_[1]);                                   \
      pst[2 * mt + 1] = pkbf(yw_[2], yw_[3]);                               \
      mloc = fmaxf(mloc, fmax4(yw_));                                       \
    }                                                                       \
    STAGE(pst)                                                              \
    bar_lds();                                                              \
    cur ^= 1;                                                               \
  }

  if (MODE == 0) {
    // ---- forward chunk: init at t0 (exact for c==0, else uniform) ----
    {
      f4 e0v[4];
      emis4(sm.obs4[n][0], e0v);  // t0 - base = 0
      mloc = 0.f;
#pragma unroll
      for (int mt = 0; mt < 4; ++mt) {
        f4 u;
        if (c == 0) {
          const f4 pi4 = *(const f4*)(lpi + jo0 + 16 * mt);
#pragma unroll
          for (int r = 0; r < 4; ++r)
            u[r] = exp2f(pi4[r] * LOG2E) * e0v[mt][r];
        } else {
          u = e0v[mt];  // uniform prior x emission
        }
        pst[2 * mt] = pkbf(u[0], u[1]);
        pst[2 * mt + 1] = pkbf(u[2], u[3]);
        mloc = fmaxf(mloc, fmax4(u));
      }
      cur = 1;
      STAGE(pst)  // -> xfrag[0]
      cur = 0;
      emis4(sm.obs4[n][t0 + 1 - base], eA);
      emis4(sm.obs4[n][t0 + 2 - base], eB);
      bar_lds();
    }
    STEPF(t0, eA)  // step count tEnd-t0 is odd (31 or 63): peel one
#pragma unroll 1
    for (int T = t0 + 1; T <= tEnd - 2; T += 2) {
      STEPF(T, eB)
      STEPF(T + 1, eA)
    }
    {  // final row tEnd
      unsigned short* op = outh + rown + (size_t)tEnd * KK + jo0;
#pragma unroll
      for (int mt = 0; mt < 4; ++mt)
        *(u2v*)(op + 16 * mt) = mku2(pst[2 * mt], pst[2 * mt + 1]);
    }
  } else {
    // ---- backward chunk: init at tS (exact beta=1 for tS==511) ----
    {
      f4 e0v[4];
      emis4(sm.obs4[n][tS - base], e0v);
      mloc = 0.f;
#pragma unroll
      for (int mt = 0; mt < 4; ++mt) {
        pst[2 * mt] = pkbf(e0v[mt][0], e0v[mt][1]);
        pst[2 * mt + 1] = pkbf(e0v[mt][2], e0v[mt][3]);
        mloc = fmaxf(mloc, fmax4(e0v[mt]));
        qst[2 * mt] = 0x3F803F80u;  // beta(tS) = 1 (2xbf16)
        qst[2 * mt + 1] = 0x3F803F80u;
      }
      cur = 1;
      STAGE(pst)  // staged w_tS -> xfrag[0]
      cur = 0;
      emis4(sm.obs4[n][tS - 1 - base], eA);
      emis4(sm.obs4[n][tS - 2 - base], eB);
      bar_lds();
    }
    STEPB(tS - 1, eA)  // step count tS-wlo is odd (31 or 63): peel one
#pragma unroll 1
    for (int T = tS - 2; T >= wlo + 1; T -= 2) {
      STEPB(T, eB)
      STEPB(T - 1, eA)
    }
    {  // final row wlo
      unsigned short* op = outh + rown + (size_t)wlo * KK + jo0;
#pragma unroll
      for (int mt = 0; mt < 4; ++mt)
        *(u2v*)(op + 16 * mt) = mku2(qst[2 * mt], qst[2 * mt + 1]);
    }
  }
#undef MFMA4
#undef STAGE
#undef SMWR
#undef RSCALE
#undef STEPF
#undef STEPB
}

__global__ __launch_bounds__(256, 1) void hmm4_chunks(
    const float* __restrict__ lpi, const float* __restrict__ lA,
    const float* __restrict__ ebT, const int* __restrict__ obs,
    unsigned short* __restrict__ aws, unsigned short* __restrict__ bws) {
  __shared__ Sm4c sm;
  const int bid = blockIdx.x;
  const int sg = bid & 15;
  const int c = (bid >> 4) & (NCH - 1);
  if (bid < NBLK * NCH)
    body4c<0>(sm, sg * SPB, c, lpi, lA, ebT, obs, aws);
  else
    body4c<2>(sm, sg * SPB, c, lpi, lA, ebT, obs, bws);
}

// ================== R12 8-wave kernels (fallback tiers) ==================
struct SmemT {
  unsigned short obs_s[SPB][520];
  b8 xfrag[2][8][64];
  float smax[2][160];
};

template <int MODE, bool TRANS>
__device__ __forceinline__ void hmm_body(
    SmemT& sm, int blk, const float* __restrict__ lpi,
    const float* __restrict__ lA, const float* __restrict__ lB,
    const float* __restrict__ ebT, const int* __restrict__ obs,
    float* __restrict__ gout) {
  const int n0 = blk * SPB;
  const int tid = threadIdx.x;
  const int w = tid >> 6;
  const int l = tid & 63;
  const int n = l & 15;
  const int q = l >> 4;
  const int j0 = 32 * w + 4 * q;

  for (int i = tid; i < SPB * TT; i += 512)
    sm.obs_s[i >> 9][i & 511] = (unsigned short)obs[(size_t)n0 * TT + i];

  b8 afrag[2][8];
#pragma unroll
  for (int mt = 0; mt < 2; ++mt) {
    const int m = (2 * w + mt) * 16 + n;
#pragma unroll
    for (int kc = 0; kc < 8; ++kc) {
      u4v tmp;
#pragma unroll
      for (int ep = 0; ep < 4; ++ep) {
        const int k = kc * 32 + q * 8 + 2 * ep;
        float v0, v1;
        if (MODE == 0) {
          v0 = lA[(size_t)k * KK + m];
          v1 = lA[(size_t)(k + 1) * KK + m];
        } else {
          v0 = lA[(size_t)m * KK + k];
          v1 = lA[(size_t)m * KK + k + 1];
        }
        tmp[ep] = (u32)f2bf_rne(exp2f(v0 * LOG2E)) |
                  ((u32)f2bf_rne(exp2f(v1 * LOG2E)) << 16);
      }
      afrag[mt][kc] = __builtin_bit_cast(b8, tmp);
    }
  }
  const int lam0 = (q >> 1) * 16 + n;
  const int e0 = (q & 1) * 4;
  __syncthreads();

  auto emis = [&](int te, f4& ea, f4& eb) {
    const int o = sm.obs_s[n][te];
    if constexpr (TRANS) {
      const float* er = ebT + (size_t)o * KK + j0;
      ea = *(const f4*)er;
      eb = *(const f4*)(er + 16);
    } else {
#pragma unroll
      for (int r = 0; r < 4; ++r) {
        ea[r] = exp2f(lB[(size_t)(j0 + r) * VV + o] * LOG2E);
        eb[r] = exp2f(lB[(size_t)(j0 + 16 + r) * VV + o] * LOG2E);
      }
    }
  };
  auto stage_write = [&](const u32 p[4], const float yv[8], int dst) {
    *(u2v*)((unsigned short*)&sm.xfrag[dst][w][lam0] + e0) = mku2(p[0], p[1]);
    *(u2v*)((unsigned short*)&sm.xfrag[dst][w][lam0 + 32] + e0) =
        mku2(p[2], p[3]);
    float m = fmaxf(fmaxf(fmaxf(yv[0], yv[1]), fmaxf(yv[2], yv[3])),
                    fmaxf(fmaxf(yv[4], yv[5]), fmaxf(yv[6], yv[7])));
    m = fmaxf(m, __shfl_xor(m, 16));
    m = fmaxf(m, __shfl_xor(m, 32));
    if (l < 16) sm.smax[dst][l * 9 + w] = m;
  };
  auto mfma_step = [&](int cur, f4& o0, f4& o1) {
    b8 bfr[8];
#pragma unroll
    for (int kc = 0; kc < 8; ++kc) bfr[kc] = sm.xfrag[cur][kc][l];
    f4 a0a = {0.f, 0.f, 0.f, 0.f}, a0b = a0a, a1a = a0a, a1b = a0a;
#pragma unroll
    for (int kc = 0; kc < 4; ++kc) {
      a0a = __builtin_amdgcn_mfma_f32_16x16x32_bf16(afrag[0][kc], bfr[kc],
                                                    a0a, 0, 0, 0);
      a1a = __builtin_amdgcn_mfma_f32_16x16x32_bf16(afrag[1][kc], bfr[kc],
                                                    a1a, 0, 0, 0);
    }
#pragma unroll
    for (int kc = 4; kc < 8; ++kc) {
      a0b = __builtin_amdgcn_mfma_f32_16x16x32_bf16(afrag[0][kc], bfr[kc],
                                                    a0b, 0, 0, 0);
      a1b = __builtin_amdgcn_mfma_f32_16x16x32_bf16(afrag[1][kc], bfr[kc],
                                                    a1b, 0, 0, 0);
    }
    o0 = a0a + a0b;
    o1 = a1a + a1b;
  };
  auto rscale = [&](int cur) -> float {
    float mm = sm.smax[cur][n * 9];
#pragma unroll
    for (int ww = 1; ww < 8; ++ww) mm = fmaxf(mm, sm.smax[cur][n * 9 + ww]);
    return __builtin_amdgcn_rcpf(fmaxf(mm, 1e-30f));
  };

  if (tid < 320) ((float*)sm.smax)[tid] = 1.0f;
  __syncthreads();

  if (MODE == 0) {
    f4 ea, eb;
    emis(0, ea, eb);
    float y0[8];
#pragma unroll
    for (int r = 0; r < 8; ++r) {
      const int jr = j0 + 16 * (r >> 2) + (r & 3);
      y0[r] = exp2f(lpi[jr] * LOG2E) * ((r < 4) ? ea[r] : eb[r - 4]);
    }
    u32 p[4] = {pkbf(y0[0], y0[1]), pkbf(y0[2], y0[3]), pkbf(y0[4], y0[5]),
                pkbf(y0[6], y0[7])};
    stage_write(p, y0, 0);
    {
      float* op = gout + ((size_t)(n0 + n) * TT + 0) * KK + j0;
      f4 v0, v1;
#pragma unroll
      for (int r = 0; r < 4; ++r) { v0[r] = y0[r]; v1[r] = y0[4 + r]; }
      *(f4*)op = v0;
      *(f4*)(op + 16) = v1;
    }
    bar_lds();
    f4 eca, ecb;
    emis(1, eca, ecb);
#pragma unroll 1
    for (int t = 0; t < TT - 1; ++t) {
      const int cur = t & 1;
      f4 pa, pb;
      emis(t + 2 < TT ? t + 2 : TT - 1, pa, pb);
      const float rs = rscale(cur);
      f4 acc0, acc1;
      mfma_step(cur, acc0, acc1);
      float yv[8];
#pragma unroll
      for (int r = 0; r < 8; ++r) {
        const float e = (r < 4) ? eca[r] : ecb[r - 4];
        const float D = (r < 4) ? acc0[r] : acc1[r - 4];
        yv[r] = D * e * rs;
      }
      u32 pp[4] = {pkbf(yv[0], yv[1]), pkbf(yv[2], yv[3]), pkbf(yv[4], yv[5]),
                   pkbf(yv[6], yv[7])};
      stage_write(pp, yv, cur ^ 1);
      {
        float* op = gout + ((size_t)(n0 + n) * TT + t + 1) * KK + j0;
        f4 v0, v1;
#pragma unroll
        for (int r = 0; r < 4; ++r) { v0[r] = yv[r]; v1[r] = yv[4 + r]; }
        *(f4*)op = v0;
        *(f4*)(op + 16) = v1;
      }
      bar_lds();
      eca = pa;
      ecb = pb;
    }
  } else {
    f4 ea, eb;
    emis(TT - 1, ea, eb);
    float y0[8];
#pragma unroll
    for (int r = 0; r < 8; ++r) y0[r] = (r < 4) ? ea[r] : eb[r - 4];
    u32 p[4] = {pkbf(y0[0], y0[1]), pkbf(y0[2], y0[3]), pkbf(y0[4], y0[5]),
                pkbf(y0[6], y0[7])};
    stage_write(p, y0, 0);
    bar_lds();
    f4 eca, ecb;
    emis(TT - 2, eca, ecb);
    f4 aa = {0.f, 0.f, 0.f, 0.f}, ab = aa;
    {
      const float* ar = gout + ((size_t)(n0 + n) * TT + (TT - 2)) * KK + j0;
      aa = *(const f4*)ar;
      ab = *(const f4*)(ar + 16);
    }
#pragma unroll 1
    for (int t = TT - 2; t >= 0; --t) {
      const int cur = (TT - 2 - t) & 1;
      const int tp = t > 0 ? t - 1 : 0;
      f4 pa, pb;
      emis(tp, pa, pb);
      f4 naa = {0.f, 0.f, 0.f, 0.f}, nab = naa;
      if (t > 0) {
        const float* ar = gout + ((size_t)(n0 + n) * TT + tp) * KK + j0;
        naa = *(const f4*)ar;
        nab = *(const f4*)(ar + 16);
      }
      const float rs = rscale(cur);
      f4 acc0, acc1;
      mfma_step(cur, acc0, acc1);
      float yv[8];
#pragma unroll
      for (int r = 0; r < 8; ++r) {
        const float bvr = (r < 4) ? acc0[r] : acc1[r - 4];
        const float e = (r < 4) ? eca[r] : ecb[r - 4];
        yv[r] = bvr * e * rs;
      }
      u32 pp[4] = {pkbf(yv[0], yv[1]), pkbf(yv[2], yv[3]), pkbf(yv[4], yv[5]),
                   pkbf(yv[6], yv[7])};
      stage_write(pp, yv, cur ^ 1);
      {
        f4 g0, g1;
#pragma unroll
        for (int r = 0; r < 4; ++r) {
          g0[r] = aa[r] * acc0[r];
          g1[r] = ab[r] * acc1[r];
        }
        float* op = gout + ((size_t)(n0 + n) * TT + t) * KK + j0;
        *(f4*)op = g0;
        *(f4*)(op + 16) = g1;
      }
      bar_lds();
      eca = pa;
      ecb = pb;
      aa = naa;
      ab = nab;
    }
  }
}

template <int MODE, bool TRANS>
__global__ __launch_bounds__(512, 1) void hmm_one(
    const float* __restrict__ lpi, const float* __restrict__ lA,
    const float* __restrict__ lB, const float* __restrict__ ebT,
    const int* __restrict__ obs, float* __restrict__ gout) {
  __shared__ SmemT sm;
  hmm_body<MODE, TRANS>(sm, blockIdx.x, lpi, lA, lB, ebT, obs, gout);
}

// ============================ streaming passes ============================
__global__ __launch_bounds__(256) void expT(const float* __restrict__ lB,
                                            float* __restrict__ ebT) {
#pragma unroll 1
  for (int v = blockIdx.x; v < VV; v += gridDim.x)
    for (int k = threadIdx.x; k < KK; k += 256)
      ebT[(size_t)v * KK + k] = exp2f(lB[(size_t)k * VV + v] * LOG2E);
}

__global__ __launch_bounds__(256) void gamma_mul16(
    float* __restrict__ gout, const unsigned short* __restrict__ aw,
    const unsigned short* __restrict__ bw) {
  const int wave = blockIdx.x * 4 + (threadIdx.x >> 6);
  const int c = threadIdx.x & 63;
  const int stride = gridDim.x * 4;
#pragma unroll 1
  for (int row = wave; row < NB * TT; row += stride) {
    const size_t base = (size_t)row * KK + c * 4;
    const u2v ua = *(const u2v*)(aw + base);
    const u2v ub = *(const u2v*)(bw + base);
    f4 v;
    v[0] = __uint_as_float(ua[0] << 16) * __uint_as_float(ub[0] << 16);
    v[1] = __uint_as_float(ua[0] & 0xFFFF0000u) *
           __uint_as_float(ub[0] & 0xFFFF0000u);
    v[2] = __uint_as_float(ua[1] << 16) * __uint_as_float(ub[1] << 16);
    v[3] = __uint_as_float(ua[1] & 0xFFFF0000u) *
           __uint_as_float(ub[1] & 0xFFFF0000u);
#pragma unroll
    for (int r = 0; r < 4; ++r) v[r] = fmaxf(v[r], 1e-37f);
    float s = (v[0] + v[1]) + (v[2] + v[3]);
#pragma unroll
    for (int d = 1; d < 64; d <<= 1) s += __shfl_xor(s, d);
    const float lg = __log2f(s);
    f4 o;
    o[0] = (__log2f(v[0]) - lg) * LN2;
    o[1] = (__log2f(v[1]) - lg) * LN2;
    o[2] = (__log2f(v[2]) - lg) * LN2;
    o[3] = (__log2f(v[3]) - lg) * LN2;
    *(f4*)(gout + base) = o;
  }
}

__global__ __launch_bounds__(256) void gamma_norm(float* __restrict__ gout) {
  const int wave = blockIdx.x * 4 + (threadIdx.x >> 6);
  const int c = threadIdx.x & 63;
  const int stride = gridDim.x * 4;
#pragma unroll 1
  for (int row = wave; row < NB * TT; row += stride) {
    float* p = gout + (size_t)row * KK + c * 4;
    const f4 v = *(const f4*)p;
    float s = (v[0] + v[1]) + (v[2] + v[3]);
#pragma unroll
    for (int d = 1; d < 64; d <<= 1) s += __shfl_xor(s, d);
    const float lg = __log2f(s);
    f4 o;
    o[0] = (__log2f(v[0]) - lg) * LN2;
    o[1] = (__log2f(v[1]) - lg) * LN2;
    o[2] = (__log2f(v[2]) - lg) * LN2;
    o[3] = (__log2f(v[3]) - lg) * LN2;
    *(f4*)p = o;
  }
}

extern "C" void kernel_launch(void* const* d_in, const int* in_sizes, int n_in,
                              void* d_out, int out_size, void* d_ws, size_t ws_size,
                              hipStream_t stream) {
  const float* lpi = (const float*)d_in[0];
  const float* lA = (const float*)d_in[1];
  const float* lB = (const float*)d_in[2];
  const int* obs = (const int*)d_in[3];
  float* gout = (float*)d_out;

  const size_t EBT_B = (size_t)VV * KK * sizeof(float);       // 4 MB
  const size_t H16_B = (size_t)NB * TT * KK * sizeof(short);  // 67 MB
  float* ebT = (float*)d_ws;
  unsigned short* aws = (unsigned short*)((char*)d_ws + EBT_B);
  unsigned short* bws = (unsigned short*)((char*)d_ws + EBT_B + H16_B);

  if (ws_size >= EBT_B + 2 * H16_B) {
    expT<<<2048, 256, 0, stream>>>(lB, ebT);
    hmm4_chunks<<<2 * NBLK * NCH, 256, 0, stream>>>(lpi, lA, ebT, obs, aws,
                                                    bws);
    gamma_mul16<<<2048, 256, 0, stream>>>(gout, aws, bws);
  } else if (ws_size >= EBT_B) {
    expT<<<2048, 256, 0, stream>>>(lB, ebT);
    hmm_one<0, true><<<NBLK, 512, 0, stream>>>(lpi, lA, lB, ebT, obs, gout);
    hmm_one<1, true><<<NBLK, 512, 0, stream>>>(lpi, lA, lB, ebT, obs, gout);
    gamma_norm<<<2048, 256, 0, stream>>>(gout);
  } else {
    hmm_one<0, false><<<NBLK, 512, 0, stream>>>(lpi, lA, lB, nullptr, obs,
                                                gout);
    hmm_one<1, false><<<NBLK, 512, 0, stream>>>(lpi, lA, lB, nullptr, obs,
                                                gout);
    gamma_norm<<<2048, 256, 0, stream>>>(gout);
  }
}

// Round 12
// 310.909 us; speedup vs baseline: 1.0397x; 1.0397x over previous
//
#include <hip/hip_runtime.h>
#include <stdint.h>

// Baum-Welch forward-backward posteriors (log_gamma), MI355X gfx950.
//
// R15 -> R16: force 2-block/CU co-residency via __launch_bounds__(256, 2).
//  - R15 counters: Occupancy 11.7% (= 1 block/CU) -> the 512 chunk-blocks
//    ran as TWO sequential rounds (226us > R14's 145us). Cause: unified
//    VGPR+AGPR footprint (af[4][8]=128 AGPR + 184 arch) > 256, and
//    launch_bounds(256,1) permitted the compiler to settle at 1 wave/SIMD.
//  - Fix: launch_bounds(256,2) caps unified regs at 256/wave -> 2 blocks
//    (2 independent chains) co-resident per CU. Per-step matrix floor is
//    515 cy vs 2740 cy measured (81% stall) -> the partner chain's issue
//    hides in the stall window nearly free.
//  - Everything else identical to R15: CL=32/CW=32 chunked recurrence
//    (warmup error < 1e-10, absmax-verified = serial), R14-proven step
//    body, deferred-by-2 scale, one lgkm-only barrier per step.
//  - Fallback tiers (small ws): R12's full-length kernels, unchanged.

#define NB 256
#define TT 512
#define KK 256
#define VV 4096
#define SPB 16            // sequences per block
#define NBLK (NB / SPB)   // 16 seq-groups
#define CL 32             // chunk length (rows written per chunk)
#define CW 32             // warmup steps
#define NCH (TT / CL)     // 16 chunks per direction
#define LOG2E 1.44269504088896f
#define LN2 0.693147180559945f

typedef float f4 __attribute__((ext_vector_type(4)));
typedef short b8 __attribute__((ext_vector_type(8)));
typedef unsigned int u32;
typedef u32 u2v __attribute__((ext_vector_type(2)));
typedef u32 u4v __attribute__((ext_vector_type(4)));

__device__ __forceinline__ void bar_lds() {
  asm volatile("s_waitcnt lgkmcnt(0)" ::: "memory");
  __builtin_amdgcn_s_barrier();
}

__device__ __forceinline__ unsigned short f2bf_rne(float x) {
  u32 u = __float_as_uint(x);
  return (unsigned short)((u + 0x7FFFu + ((u >> 16) & 1u)) >> 16);
}
// pack two positive floats to 2xbf16 (round-half-up) in one v_perm each.
__device__ __forceinline__ u32 pkbf(float lo, float hi) {
  return __builtin_amdgcn_perm(__float_as_uint(hi) + 0x8000u,
                               __float_as_uint(lo) + 0x8000u, 0x07060302u);
}
__device__ __forceinline__ u2v mku2(u32 a, u32 b) {
  u2v v; v[0] = a; v[1] = b; return v;
}
__device__ __forceinline__ float fmax4(const f4& v) {
  return fmaxf(fmaxf(v[0], v[1]), fmaxf(v[2], v[3]));
}

// ==================== chunked 4-wave MFMA recurrence ====================
struct Sm4c {
  unsigned short obs4[SPB][72];        // 2.3 KB chunk obs window
  b8 xfrag[2][8][64];                  // 16 KB ping-pong B fragments
  __align__(16) float smax[2][16][4];  // deferred per-seq max partials
};

// MODE 0: forward chunk -> bf16 scaled-alpha rows [wlo, wlo+CL) of outh.
// MODE 2: backward chunk -> bf16 scaled-beta rows [wlo, wlo+CL) (last chunk
//         also writes row 511 = 1).
template <int MODE>
__device__ __forceinline__ void body4c(Sm4c& sm, int n0, int c,
                                       const float* __restrict__ lpi,
                                       const float* __restrict__ lA,
                                       const float* __restrict__ ebT,
                                       const int* __restrict__ obs,
                                       unsigned short* __restrict__ outh) {
  const int tid = threadIdx.x;  // 0..255
  const int w = tid >> 6;       // wave 0..3: owns states [64w, 64w+64)
  const int l = tid & 63;
  const int n = l & 15;         // sequence slot
  const int q = l >> 4;         // 0..3
  const int jo0 = 64 * w + 4 * q;

  // Chunk ranges.
  const int wlo = c * CL;
  int t0 = 0, tEnd = 0, tS = 0, whi = 0, base, tmax;
  if (MODE == 0) {
    tEnd = wlo + CL - 1;
    t0 = (c == 0) ? 0 : wlo - CW;
    base = t0;
    tmax = tEnd;
  } else {
    whi = wlo + CL;
    tS = whi + CW - 1;
    if (tS > TT - 1) tS = TT - 1;
    base = wlo;
    tmax = tS;
  }
  const int win = tmax - base + 1;  // <= 64

  for (int i = tid; i < SPB * 64; i += 256) {
    const int s = i >> 6, k = i & 63;
    if (k < win)
      sm.obs4[s][k] = (unsigned short)obs[(size_t)(n0 + s) * TT + base + k];
  }

  // A fragments: tile = 4w+mt, m = 16*tile + n, k = kc*32 + q*8 + e.
  // fwd: expA[k][m] (A^T); bwd: expA[m][k] (A).
  b8 af[4][8];
#pragma unroll
  for (int mt = 0; mt < 4; ++mt) {
    const int m = 16 * (4 * w + mt) + n;
#pragma unroll
    for (int kc = 0; kc < 8; ++kc) {
      u4v tmp;
#pragma unroll
      for (int ep = 0; ep < 4; ++ep) {
        const int k = kc * 32 + q * 8 + 2 * ep;
        float v0, v1;
        if (MODE == 0) {
          v0 = lA[(size_t)k * KK + m];
          v1 = lA[(size_t)(k + 1) * KK + m];
        } else {
          v0 = lA[(size_t)m * KK + k];
          v1 = lA[(size_t)m * KK + k + 1];
        }
        tmp[ep] = pkbf(exp2f(v0 * LOG2E), exp2f(v1 * LOG2E));
      }
      af[mt][kc] = __builtin_bit_cast(b8, tmp);
    }
  }

  // Staging map (R10-verified): plane kc = tile>>1;
  // ushort index = 8*(n + 16*(q>>1) + 32*(tile&1)) + 4*(q&1).
  int usb[4];
#pragma unroll
  for (int mt = 0; mt < 4; ++mt) {
    const int tile = 4 * w + mt;
    usb[mt] = 8 * (n + 16 * (q >> 1) + 32 * (tile & 1)) + 4 * (q & 1);
  }
  const int kcp[4] = {(4 * w) >> 1, (4 * w) >> 1, (4 * w + 2) >> 1,
                      (4 * w + 2) >> 1};

  if (tid < 128) ((float*)sm.smax)[tid] = 1.0f;  // seed both slots
  __syncthreads();

  const size_t rown = (size_t)(n0 + n) * TT * KK;
  u32 pst[8], qst[8];
  float mloc = 0.f;
  f4 eA[4], eB[4];
  int cur = 0;

  auto emis4 = [&](int o, f4 e[4]) {
    const float* er = ebT + (size_t)o * KK + jo0;
#pragma unroll
    for (int mt = 0; mt < 4; ++mt) e[mt] = *(const f4*)(er + 16 * mt);
  };

#define MFMA4(ACC)                                                          \
  {                                                                         \
    b8 bfr[8];                                                              \
    _Pragma("unroll") for (int kc = 0; kc < 8; ++kc) bfr[kc] =              \
        sm.xfrag[cur][kc][l];                                               \
    _Pragma("unroll") for (int mt = 0; mt < 4; ++mt) {                      \
      f4 ca = {0.f, 0.f, 0.f, 0.f}, cb = ca;                                \
      _Pragma("unroll") for (int kc = 0; kc < 4; ++kc) ca =                 \
          __builtin_amdgcn_mfma_f32_16x16x32_bf16(af[mt][kc], bfr[kc], ca,  \
                                                  0, 0, 0);                 \
      _Pragma("unroll") for (int kc = 4; kc < 8; ++kc) cb =                 \
          __builtin_amdgcn_mfma_f32_16x16x32_bf16(af[mt][kc], bfr[kc], cb,  \
                                                  0, 0, 0);                 \
      ACC[mt] = ca + cb;                                                    \
    }                                                                       \
  }

#define STAGE(P)                                                            \
  _Pragma("unroll") for (int mt = 0; mt < 4; ++mt)                          \
      *(u2v*)((unsigned short*)&sm.xfrag[cur ^ 1][kcp[mt]][0] + usb[mt]) =  \
          mku2(P[2 * mt], P[2 * mt + 1]);

#define SMWR()                                                              \
  {                                                                         \
    float mm_ = fmaxf(mloc, __shfl_xor(mloc, 16));                          \
    mm_ = fmaxf(mm_, __shfl_xor(mm_, 32));                                  \
    if (l < 16) sm.smax[cur][n][w] = mm_;                                   \
  }

#define RSCALE(RS)                                                          \
  const f4 sm4_ = *(const f4*)&sm.smax[cur ^ 1][n][0];                      \
  const float RS = __builtin_amdgcn_rcpf(fmaxf(fmax4(sm4_), 1e-30f));

#define STEPF(T_, EU)                                                       \
  {                                                                         \
    const int tt_ = (T_);                                                   \
    if (tt_ >= wlo) { /* deferred store of row tt_ */                       \
      unsigned short* op_ = outh + rown + (size_t)tt_ * KK + jo0;           \
      _Pragma("unroll") for (int mt = 0; mt < 4; ++mt)                      \
          *(u2v*)(op_ + 16 * mt) = mku2(pst[2 * mt], pst[2 * mt + 1]);      \
    }                                                                       \
    SMWR()                                                                  \
    RSCALE(rs_)                                                             \
    const f4 ec0 = EU[0], ec1 = EU[1], ec2 = EU[2], ec3 = EU[3];            \
    const int o3_ = sm.obs4[n][(tt_ + 3 <= tEnd ? tt_ + 3 : tEnd) - base];  \
    emis4(o3_, EU);                                                         \
    f4 acc[4];                                                              \
    MFMA4(acc)                                                              \
    const f4 ecs_[4] = {ec0, ec1, ec2, ec3};                                \
    mloc = 0.f;                                                             \
    _Pragma("unroll") for (int mt = 0; mt < 4; ++mt) {                      \
      const f4 y_ = acc[mt] * (ecs_[mt] * rs_);                             \
      pst[2 * mt] = pkbf(y_[0], y_[1]);                                     \
      pst[2 * mt + 1] = pkbf(y_[2], y_[3]);                                 \
      mloc = fmaxf(mloc, fmax4(y_));                                        \
    }                                                                       \
    STAGE(pst)                                                              \
    bar_lds();                                                              \
    cur ^= 1;                                                               \
  }

#define STEPB(T_, EU)                                                       \
  {                                                                         \
    const int tt_ = (T_);                                                   \
    if (tt_ + 1 < whi) { /* deferred store of beta row tt_+1 */             \
      unsigned short* op_ = outh + rown + (size_t)(tt_ + 1) * KK + jo0;     \
      _Pragma("unroll") for (int mt = 0; mt < 4; ++mt)                      \
          *(u2v*)(op_ + 16 * mt) = mku2(qst[2 * mt], qst[2 * mt + 1]);      \
    }                                                                       \
    SMWR()                                                                  \
    RSCALE(rs_)                                                             \
    const f4 ec0 = EU[0], ec1 = EU[1], ec2 = EU[2], ec3 = EU[3];            \
    const int o2_ = sm.obs4[n][(tt_ >= wlo + 2 ? tt_ - 2 : wlo) - base];    \
    emis4(o2_, EU);                                                         \
    f4 acc[4];                                                              \
    MFMA4(acc)                                                              \
    const f4 ecs_[4] = {ec0, ec1, ec2, ec3};                                \
    mloc = 0.f;                                                             \
    _Pragma("unroll") for (int mt = 0; mt < 4; ++mt) {                      \
      const f4 bsc_ = acc[mt] * rs_;        /* scaled beta_t */             \
      const f4 yw_ = bsc_ * ecs_[mt];       /* staged w_t */                \
      qst[2 * mt] = pkbf(bsc_[0], bsc_[1]);                                 \
      qst[2 * mt + 1] = pkbf(bsc_[2], bsc_[3]);                             \
      pst[2 * mt] = pkbf(yw_[0], yw_[1]);                                   \
      pst[2 * mt + 1] = pkbf(yw_[2], yw_[3]);                               \
      mloc = fmaxf(mloc, fmax4(yw_));                                       \
    }                                                                       \
    STAGE(pst)                                                              \
    bar_lds();                                                              \
    cur ^= 1;                                                               \
  }

  if (MODE == 0) {
    // ---- forward chunk: init at t0 (exact for c==0, else uniform) ----
    {
      f4 e0v[4];
      emis4(sm.obs4[n][0], e0v);  // t0 - base = 0
      mloc = 0.f;
#pragma unroll
      for (int mt = 0; mt < 4; ++mt) {
        f4 u;
        if (c == 0) {
          const f4 pi4 = *(const f4*)(lpi + jo0 + 16 * mt);
#pragma unroll
          for (int r = 0; r < 4; ++r)
            u[r] = exp2f(pi4[r] * LOG2E) * e0v[mt][r];
        } else {
          u = e0v[mt];  // uniform prior x emission
        }
        pst[2 * mt] = pkbf(u[0], u[1]);
        pst[2 * mt + 1] = pkbf(u[2], u[3]);
        mloc = fmaxf(mloc, fmax4(u));
      }
      cur = 1;
      STAGE(pst)  // -> xfrag[0]
      cur = 0;
      emis4(sm.obs4[n][t0 + 1 - base], eA);
      emis4(sm.obs4[n][t0 + 2 - base], eB);
      bar_lds();
    }
    STEPF(t0, eA)  // step count tEnd-t0 is odd (31 or 63): peel one
#pragma unroll 1
    for (int T = t0 + 1; T <= tEnd - 2; T += 2) {
      STEPF(T, eB)
      STEPF(T + 1, eA)
    }
    {  // final row tEnd
      unsigned short* op = outh + rown + (size_t)tEnd * KK + jo0;
#pragma unroll
      for (int mt = 0; mt < 4; ++mt)
        *(u2v*)(op + 16 * mt) = mku2(pst[2 * mt], pst[2 * mt + 1]);
    }
  } else {
    // ---- backward chunk: init at tS (exact beta=1 for tS==511) ----
    {
      f4 e0v[4];
      emis4(sm.obs4[n][tS - base], e0v);
      mloc = 0.f;
#pragma unroll
      for (int mt = 0; mt < 4; ++mt) {
        pst[2 * mt] = pkbf(e0v[mt][0], e0v[mt][1]);
        pst[2 * mt + 1] = pkbf(e0v[mt][2], e0v[mt][3]);
        mloc = fmaxf(mloc, fmax4(e0v[mt]));
        qst[2 * mt] = 0x3F803F80u;  // beta(tS) = 1 (2xbf16)
        qst[2 * mt + 1] = 0x3F803F80u;
      }
      cur = 1;
      STAGE(pst)  // staged w_tS -> xfrag[0]
      cur = 0;
      emis4(sm.obs4[n][tS - 1 - base], eA);
      emis4(sm.obs4[n][tS - 2 - base], eB);
      bar_lds();
    }
    STEPB(tS - 1, eA)  // step count tS-wlo is odd (31 or 63): peel one
#pragma unroll 1
    for (int T = tS - 2; T >= wlo + 1; T -= 2) {
      STEPB(T, eB)
      STEPB(T - 1, eA)
    }
    {  // final row wlo
      unsigned short* op = outh + rown + (size_t)wlo * KK + jo0;
#pragma unroll
      for (int mt = 0; mt < 4; ++mt)
        *(u2v*)(op + 16 * mt) = mku2(qst[2 * mt], qst[2 * mt + 1]);
    }
  }
#undef MFMA4
#undef STAGE
#undef SMWR
#undef RSCALE
#undef STEPF
#undef STEPB
}

__global__ __launch_bounds__(256, 2) void hmm4_chunks(
    const float* __restrict__ lpi, const float* __restrict__ lA,
    const float* __restrict__ ebT, const int* __restrict__ obs,
    unsigned short* __restrict__ aws, unsigned short* __restrict__ bws) {
  __shared__ Sm4c sm;
  const int bid = blockIdx.x;
  const int sg = bid & 15;
  const int c = (bid >> 4) & (NCH - 1);
  if (bid < NBLK * NCH)
    body4c<0>(sm, sg * SPB, c, lpi, lA, ebT, obs, aws);
  else
    body4c<2>(sm, sg * SPB, c, lpi, lA, ebT, obs, bws);
}

// ================== R12 8-wave kernels (fallback tiers) ==================
struct SmemT {
  unsigned short obs_s[SPB][520];
  b8 xfrag[2][8][64];
  float smax[2][160];
};

template <int MODE, bool TRANS>
__device__ __forceinline__ void hmm_body(
    SmemT& sm, int blk, const float* __restrict__ lpi,
    const float* __restrict__ lA, const float* __restrict__ lB,
    const float* __restrict__ ebT, const int* __restrict__ obs,
    float* __restrict__ gout) {
  const int n0 = blk * SPB;
  const int tid = threadIdx.x;
  const int w = tid >> 6;
  const int l = tid & 63;
  const int n = l & 15;
  const int q = l >> 4;
  const int j0 = 32 * w + 4 * q;

  for (int i = tid; i < SPB * TT; i += 512)
    sm.obs_s[i >> 9][i & 511] = (unsigned short)obs[(size_t)n0 * TT + i];

  b8 afrag[2][8];
#pragma unroll
  for (int mt = 0; mt < 2; ++mt) {
    const int m = (2 * w + mt) * 16 + n;
#pragma unroll
    for (int kc = 0; kc < 8; ++kc) {
      u4v tmp;
#pragma unroll
      for (int ep = 0; ep < 4; ++ep) {
        const int k = kc * 32 + q * 8 + 2 * ep;
        float v0, v1;
        if (MODE == 0) {
          v0 = lA[(size_t)k * KK + m];
          v1 = lA[(size_t)(k + 1) * KK + m];
        } else {
          v0 = lA[(size_t)m * KK + k];
          v1 = lA[(size_t)m * KK + k + 1];
        }
        tmp[ep] = (u32)f2bf_rne(exp2f(v0 * LOG2E)) |
                  ((u32)f2bf_rne(exp2f(v1 * LOG2E)) << 16);
      }
      afrag[mt][kc] = __builtin_bit_cast(b8, tmp);
    }
  }
  const int lam0 = (q >> 1) * 16 + n;
  const int e0 = (q & 1) * 4;
  __syncthreads();

  auto emis = [&](int te, f4& ea, f4& eb) {
    const int o = sm.obs_s[n][te];
    if constexpr (TRANS) {
      const float* er = ebT + (size_t)o * KK + j0;
      ea = *(const f4*)er;
      eb = *(const f4*)(er + 16);
    } else {
#pragma unroll
      for (int r = 0; r < 4; ++r) {
        ea[r] = exp2f(lB[(size_t)(j0 + r) * VV + o] * LOG2E);
        eb[r] = exp2f(lB[(size_t)(j0 + 16 + r) * VV + o] * LOG2E);
      }
    }
  };
  auto stage_write = [&](const u32 p[4], const float yv[8], int dst) {
    *(u2v*)((unsigned short*)&sm.xfrag[dst][w][lam0] + e0) = mku2(p[0], p[1]);
    *(u2v*)((unsigned short*)&sm.xfrag[dst][w][lam0 + 32] + e0) =
        mku2(p[2], p[3]);
    float m = fmaxf(fmaxf(fmaxf(yv[0], yv[1]), fmaxf(yv[2], yv[3])),
                    fmaxf(fmaxf(yv[4], yv[5]), fmaxf(yv[6], yv[7])));
    m = fmaxf(m, __shfl_xor(m, 16));
    m = fmaxf(m, __shfl_xor(m, 32));
    if (l < 16) sm.smax[dst][l * 9 + w] = m;
  };
  auto mfma_step = [&](int cur, f4& o0, f4& o1) {
    b8 bfr[8];
#pragma unroll
    for (int kc = 0; kc < 8; ++kc) bfr[kc] = sm.xfrag[cur][kc][l];
    f4 a0a = {0.f, 0.f, 0.f, 0.f}, a0b = a0a, a1a = a0a, a1b = a0a;
#pragma unroll
    for (int kc = 0; kc < 4; ++kc) {
      a0a = __builtin_amdgcn_mfma_f32_16x16x32_bf16(afrag[0][kc], bfr[kc],
                                                    a0a, 0, 0, 0);
      a1a = __builtin_amdgcn_mfma_f32_16x16x32_bf16(afrag[1][kc], bfr[kc],
                                                    a1a, 0, 0, 0);
    }
#pragma unroll
    for (int kc = 4; kc < 8; ++kc) {
      a0b = __builtin_amdgcn_mfma_f32_16x16x32_bf16(afrag[0][kc], bfr[kc],
                                                    a0b, 0, 0, 0);
      a1b = __builtin_amdgcn_mfma_f32_16x16x32_bf16(afrag[1][kc], bfr[kc],
                                                    a1b, 0, 0, 0);
    }
    o0 = a0a + a0b;
    o1 = a1a + a1b;
  };
  auto rscale = [&](int cur) -> float {
    float mm = sm.smax[cur][n * 9];
#pragma unroll
    for (int ww = 1; ww < 8; ++ww) mm = fmaxf(mm, sm.smax[cur][n * 9 + ww]);
    return __builtin_amdgcn_rcpf(fmaxf(mm, 1e-30f));
  };

  if (tid < 320) ((float*)sm.smax)[tid] = 1.0f;
  __syncthreads();

  if (MODE == 0) {
    f4 ea, eb;
    emis(0, ea, eb);
    float y0[8];
#pragma unroll
    for (int r = 0; r < 8; ++r) {
      const int jr = j0 + 16 * (r >> 2) + (r & 3);
      y0[r] = exp2f(lpi[jr] * LOG2E) * ((r < 4) ? ea[r] : eb[r - 4]);
    }
    u32 p[4] = {pkbf(y0[0], y0[1]), pkbf(y0[2], y0[3]), pkbf(y0[4], y0[5]),
                pkbf(y0[6], y0[7])};
    stage_write(p, y0, 0);
    {
      float* op = gout + ((size_t)(n0 + n) * TT + 0) * KK + j0;
      f4 v0, v1;
#pragma unroll
      for (int r = 0; r < 4; ++r) { v0[r] = y0[r]; v1[r] = y0[4 + r]; }
      *(f4*)op = v0;
      *(f4*)(op + 16) = v1;
    }
    bar_lds();
    f4 eca, ecb;
    emis(1, eca, ecb);
#pragma unroll 1
    for (int t = 0; t < TT - 1; ++t) {
      const int cur = t & 1;
      f4 pa, pb;
      emis(t + 2 < TT ? t + 2 : TT - 1, pa, pb);
      const float rs = rscale(cur);
      f4 acc0, acc1;
      mfma_step(cur, acc0, acc1);
      float yv[8];
#pragma unroll
      for (int r = 0; r < 8; ++r) {
        const float e = (r < 4) ? eca[r] : ecb[r - 4];
        const float D = (r < 4) ? acc0[r] : acc1[r - 4];
        yv[r] = D * e * rs;
      }
      u32 pp[4] = {pkbf(yv[0], yv[1]), pkbf(yv[2], yv[3]), pkbf(yv[4], yv[5]),
                   pkbf(yv[6], yv[7])};
      stage_write(pp, yv, cur ^ 1);
      {
        float* op = gout + ((size_t)(n0 + n) * TT + t + 1) * KK + j0;
        f4 v0, v1;
#pragma unroll
        for (int r = 0; r < 4; ++r) { v0[r] = yv[r]; v1[r] = yv[4 + r]; }
        *(f4*)op = v0;
        *(f4*)(op + 16) = v1;
      }
      bar_lds();
      eca = pa;
      ecb = pb;
    }
  } else {
    f4 ea, eb;
    emis(TT - 1, ea, eb);
    float y0[8];
#pragma unroll
    for (int r = 0; r < 8; ++r) y0[r] = (r < 4) ? ea[r] : eb[r - 4];
    u32 p[4] = {pkbf(y0[0], y0[1]), pkbf(y0[2], y0[3]), pkbf(y0[4], y0[5]),
                pkbf(y0[6], y0[7])};
    stage_write(p, y0, 0);
    bar_lds();
    f4 eca, ecb;
    emis(TT - 2, eca, ecb);
    f4 aa = {0.f, 0.f, 0.f, 0.f}, ab = aa;
    {
      const float* ar = gout + ((size_t)(n0 + n) * TT + (TT - 2)) * KK + j0;
      aa = *(const f4*)ar;
      ab = *(const f4*)(ar + 16);
    }
#pragma unroll 1
    for (int t = TT - 2; t >= 0; --t) {
      const int cur = (TT - 2 - t) & 1;
      const int tp = t > 0 ? t - 1 : 0;
      f4 pa, pb;
      emis(tp, pa, pb);
      f4 naa = {0.f, 0.f, 0.f, 0.f}, nab = naa;
      if (t > 0) {
        const float* ar = gout + ((size_t)(n0 + n) * TT + tp) * KK + j0;
        naa = *(const f4*)ar;
        nab = *(const f4*)(ar + 16);
      }
      const float rs = rscale(cur);
      f4 acc0, acc1;
      mfma_step(cur, acc0, acc1);
      float yv[8];
#pragma unroll
      for (int r = 0; r < 8; ++r) {
        const float bvr = (r < 4) ? acc0[r] : acc1[r - 4];
        const float e = (r < 4) ? eca[r] : ecb[r - 4];
        yv[r] = bvr * e * rs;
      }
      u32 pp[4] = {pkbf(yv[0], yv[1]), pkbf(yv[2], yv[3]), pkbf(yv[4], yv[5]),
                   pkbf(yv[6], yv[7])};
      stage_write(pp, yv, cur ^ 1);
      {
        f4 g0, g1;
#pragma unroll
        for (int r = 0; r < 4; ++r) {
          g0[r] = aa[r] * acc0[r];
          g1[r] = ab[r] * acc1[r];
        }
        float* op = gout + ((size_t)(n0 + n) * TT + t) * KK + j0;
        *(f4*)op = g0;
        *(f4*)(op + 16) = g1;
      }
      bar_lds();
      eca = pa;
      ecb = pb;
      aa = naa;
      ab = nab;
    }
  }
}

template <int MODE, bool TRANS>
__global__ __launch_bounds__(512, 1) void hmm_one(
    const float* __restrict__ lpi, const float* __restrict__ lA,
    const float* __restrict__ lB, const float* __restrict__ ebT,
    const int* __restrict__ obs, float* __restrict__ gout) {
  __shared__ SmemT sm;
  hmm_body<MODE, TRANS>(sm, blockIdx.x, lpi, lA, lB, ebT, obs, gout);
}

// ============================ streaming passes ============================
__global__ __launch_bounds__(256) void expT(const float* __restrict__ lB,
                                            float* __restrict__ ebT) {
#pragma unroll 1
  for (int v = blockIdx.x; v < VV; v += gridDim.x)
    for (int k = threadIdx.x; k < KK; k += 256)
      ebT[(size_t)v * KK + k] = exp2f(lB[(size_t)k * VV + v] * LOG2E);
}

__global__ __launch_bounds__(256) void gamma_mul16(
    float* __restrict__ gout, const unsigned short* __restrict__ aw,
    const unsigned short* __restrict__ bw) {
  const int wave = blockIdx.x * 4 + (threadIdx.x >> 6);
  const int c = threadIdx.x & 63;
  const int stride = gridDim.x * 4;
#pragma unroll 1
  for (int row = wave; row < NB * TT; row += stride) {
    const size_t base = (size_t)row * KK + c * 4;
    const u2v ua = *(const u2v*)(aw + base);
    const u2v ub = *(const u2v*)(bw + base);
    f4 v;
    v[0] = __uint_as_float(ua[0] << 16) * __uint_as_float(ub[0] << 16);
    v[1] = __uint_as_float(ua[0] & 0xFFFF0000u) *
           __uint_as_float(ub[0] & 0xFFFF0000u);
    v[2] = __uint_as_float(ua[1] << 16) * __uint_as_float(ub[1] << 16);
    v[3] = __uint_as_float(ua[1] & 0xFFFF0000u) *
           __uint_as_float(ub[1] & 0xFFFF0000u);
#pragma unroll
    for (int r = 0; r < 4; ++r) v[r] = fmaxf(v[r], 1e-37f);
    float s = (v[0] + v[1]) + (v[2] + v[3]);
#pragma unroll
    for (int d = 1; d < 64; d <<= 1) s += __shfl_xor(s, d);
    const float lg = __log2f(s);
    f4 o;
    o[0] = (__log2f(v[0]) - lg) * LN2;
    o[1] = (__log2f(v[1]) - lg) * LN2;
    o[2] = (__log2f(v[2]) - lg) * LN2;
    o[3] = (__log2f(v[3]) - lg) * LN2;
    *(f4*)(gout + base) = o;
  }
}

__global__ __launch_bounds__(256) void gamma_norm(float* __restrict__ gout) {
  const int wave = blockIdx.x * 4 + (threadIdx.x >> 6);
  const int c = threadIdx.x & 63;
  const int stride = gridDim.x * 4;
#pragma unroll 1
  for (int row = wave; row < NB * TT; row += stride) {
    float* p = gout + (size_t)row * KK + c * 4;
    const f4 v = *(const f4*)p;
    float s = (v[0] + v[1]) + (v[2] + v[3]);
#pragma unroll
    for (int d = 1; d < 64; d <<= 1) s += __shfl_xor(s, d);
    const float lg = __log2f(s);
    f4 o;
    o[0] = (__log2f(v[0]) - lg) * LN2;
    o[1] = (__log2f(v[1]) - lg) * LN2;
    o[2] = (__log2f(v[2]) - lg) * LN2;
    o[3] = (__log2f(v[3]) - lg) * LN2;
    *(f4*)p = o;
  }
}

extern "C" void kernel_launch(void* const* d_in, const int* in_sizes, int n_in,
                              void* d_out, int out_size, void* d_ws, size_t ws_size,
                              hipStream_t stream) {
  const float* lpi = (const float*)d_in[0];
  const float* lA = (const float*)d_in[1];
  const float* lB = (const float*)d_in[2];
  const int* obs = (const int*)d_in[3];
  float* gout = (float*)d_out;

  const size_t EBT_B = (size_t)VV * KK * sizeof(float);       // 4 MB
  const size_t H16_B = (size_t)NB * TT * KK * sizeof(short);  // 67 MB
  float* ebT = (float*)d_ws;
  unsigned short* aws = (unsigned short*)((char*)d_ws + EBT_B);
  unsigned short* bws = (unsigned short*)((char*)d_ws + EBT_B + H16_B);

  if (ws_size >= EBT_B + 2 * H16_B) {
    expT<<<2048, 256, 0, stream>>>(lB, ebT);
    hmm4_chunks<<<2 * NBLK * NCH, 256, 0, stream>>>(lpi, lA, ebT, obs, aws,
                                                    bws);
    gamma_mul16<<<2048, 256, 0, stream>>>(gout, aws, bws);
  } else if (ws_size >= EBT_B) {
    expT<<<2048, 256, 0, stream>>>(lB, ebT);
    hmm_one<0, true><<<NBLK, 512, 0, stream>>>(lpi, lA, lB, ebT, obs, gout);
    hmm_one<1, true><<<NBLK, 512, 0, stream>>>(lpi, lA, lB, ebT, obs, gout);
    gamma_norm<<<2048, 256, 0, stream>>>(gout);
  } else {
    hmm_one<0, false><<<NBLK, 512, 0, stream>>>(lpi, lA, lB, nullptr, obs,
                                                gout);
    hmm_one<1, false><<<NBLK, 512, 0, stream>>>(lpi, lA, lB, nullptr, obs,
                                                gout);
    gamma_norm<<<2048, 256, 0, stream>>>(gout);
  }
}